// Round 10
// baseline (209.426 us; speedup 1.0000x reference)
//
#include <hip/hip_runtime.h>
#include <math.h>

// Problem constants
#define NB 32
#define NC 64
#define NHW 3136          // 56*56
#define NM 6
#define NDIM 192
#define NHEADS 8
#define NINNER 512        // NHEADS*NC
#define NKV 3072          // NHEADS*NM*NC per batch
#define CHW (NC * NHW)    // 200704
#define NG 48             // NHEADS*NM

// ---------------------------------------------------------------------------
// MEASUREMENT ROUND: identical kernels to R9, but attn launched 5x
// (idempotent: same inputs -> same out). attn_time = (dur - 120.7)/4.
// ---------------------------------------------------------------------------

__global__ __launch_bounds__(1024) void kv_proj_kernel(
    const float* __restrict__ z, const float* __restrict__ Wk,
    const float* __restrict__ bk, const float* __restrict__ Wv,
    const float* __restrict__ bv, const float* __restrict__ Wo,
    float* __restrict__ kt, float* __restrict__ vw) {
  const int b = blockIdx.x;
  const int chunk = blockIdx.y;
  const int tid = threadIdx.x;
  const int u = tid & 255;
  const int s = __builtin_amdgcn_readfirstlane(tid >> 8);  // 0..3, SGPR
  const int idx = chunk * 256 + u;     // raw flat 0..3071
  const int mtok = chunk >> 1;         // raw row (uniform per block)
  const int i = idx & 511;             // raw col (inner)

  __shared__ float kp[1024];
  __shared__ float vp[1024];
  __shared__ float vs[256];

  const float* __restrict__ zr = z + b * (NM * NDIM) + mtok * NDIM;  // uniform

  float ak0 = 0.f, ak1 = 0.f, av0 = 0.f, av1 = 0.f;
  const int dlo = s * 48;
  #pragma unroll 8
  for (int d = dlo; d < dlo + 48; d += 2) {
    const float z0 = zr[d], z1 = zr[d + 1];
    ak0 = fmaf(z0, Wk[d * NINNER + i], ak0);
    ak1 = fmaf(z1, Wk[(d + 1) * NINNER + i], ak1);
    av0 = fmaf(z0, Wv[d * NINNER + i], av0);
    av1 = fmaf(z1, Wv[(d + 1) * NINNER + i], av1);
  }
  kp[tid] = ak0 + ak1;
  vp[tid] = av0 + av1;
  __syncthreads();

  if (tid < 256) {
    const float kf = bk[i] + ((kp[u] + kp[256 + u]) + (kp[512 + u] + kp[768 + u]));
    const float vf = bv[i] + ((vp[u] + vp[256 + u]) + (vp[512 + u] + vp[768 + u]));
    // Reshape-view decomposition of raw flat idx -> kt[h][cc][mm]
    const int h2 = idx / 384;
    const int mm2 = (idx >> 6) % 6;
    const int cc2 = idx & 63;
    kt[b * NKV + h2 * (NC * NM) + cc2 * NM + mm2] = kf;
    vs[u] = vf;
  }
  __syncthreads();

  if (tid < 256) {
    const int gl = u >> 6;             // 0..3 (uniform per wave)
    const int c = u & 63;
    const int g = chunk * 4 + gl;      // 0..47
    const int h = g / 6;
    float a0 = 0.f, a1 = 0.f;
    #pragma unroll 8
    for (int cc = 0; cc < NC; cc += 2) {
      a0 = fmaf(vs[gl * 64 + cc],     Wo[(h * NC + cc) * NC + c],     a0);
      a1 = fmaf(vs[gl * 64 + cc + 1], Wo[(h * NC + cc + 1) * NC + c], a1);
    }
    vw[b * NKV + g * NC + c] = a0 + a1;
  }
}

__global__ __launch_bounds__(512, 4) void attn_kernel(
    const float* __restrict__ x, const float* __restrict__ kt,
    const float* __restrict__ vw, const float* __restrict__ bo,
    float* __restrict__ out) {
  const int b = blockIdx.x;
  const int lane = threadIdx.x & 63;
  const int w = __builtin_amdgcn_readfirstlane((int)(threadIdx.x >> 6));  // 0..7
  const float* __restrict__ xb = x + (size_t)b * CHW;

  __shared__ float qs[NC][64];   // [c][n_local], 16 KB
  __shared__ float aw[NG][64];   // [g][n_local], 12 KB

  const float* __restrict__ kh = kt + b * NKV + w * (NC * NM);  // uniform
  const int c0 = w * 8;
  const float* __restrict__ vb = vw + b * NKV + c0;             // uniform
  const float4 bo0 = *(const float4*)(bo + c0);
  const float4 bo1 = *(const float4*)(bo + c0 + 4);
  const float scale = 0.125f;  // 64^-0.5

  #pragma unroll 1
  for (int rep = 0; rep < 2; ++rep) {
    const int tile = blockIdx.y * 2 + rep;   // block-uniform
    if (tile < 49) {
      const int n0 = tile * 64;

      // ---- stage q tile: 2 coalesced float4 per thread ----
      {
        const int tc = threadIdx.x >> 4;          // 0..31
        const int tn4 = (threadIdx.x & 15) * 4;   // 0..60
        #pragma unroll
        for (int r2 = 0; r2 < 2; ++r2) {
          const int c = tc + r2 * 32;
          *(float4*)(&qs[c][tn4]) =
              *(const float4*)(xb + (size_t)c * NHW + n0 + tn4);
        }
      }
      __syncthreads();

      // ---- phase 1: head w; kt head block = 384 sequential floats ----
      float d[NM];
      #pragma unroll
      for (int mm = 0; mm < NM; ++mm) d[mm] = 0.f;

      #pragma unroll 8
      for (int cc = 0; cc < NC; ++cc) {
        const float qv = qs[cc][lane];       // ds_read_b32, conflict-free
        #pragma unroll
        for (int mm = 0; mm < NM; ++mm)
          d[mm] = fmaf(qv, kh[cc * NM + mm], d[mm]);
      }

      {
        float mx = d[0];
        #pragma unroll
        for (int mm = 1; mm < NM; ++mm) mx = fmaxf(mx, d[mm]);
        float e[NM], ssum = 0.f;
        #pragma unroll
        for (int mm = 0; mm < NM; ++mm) {
          e[mm] = __expf((d[mm] - mx) * scale);
          ssum += e[mm];
        }
        const float r = 1.0f / ssum;
        #pragma unroll
        for (int mm = 0; mm < NM; ++mm) aw[w * NM + mm][lane] = e[mm] * r;
      }
      __syncthreads();

      // ---- phase 2: channels [8w, 8w+8) over all 48 (h,m) ----
      float4 o0 = {0, 0, 0, 0}, o1 = {0, 0, 0, 0};
      #pragma unroll 4
      for (int g = 0; g < NG; ++g) {
        const float a = aw[g][lane];         // ds_read_b32, conflict-free
        const float4 v0 = *(const float4*)(vb + g * NC);
        const float4 v1 = *(const float4*)(vb + g * NC + 4);
        o0.x = fmaf(a, v0.x, o0.x); o0.y = fmaf(a, v0.y, o0.y);
        o0.z = fmaf(a, v0.z, o0.z); o0.w = fmaf(a, v0.w, o0.w);
        o1.x = fmaf(a, v1.x, o1.x); o1.y = fmaf(a, v1.y, o1.y);
        o1.z = fmaf(a, v1.z, o1.z); o1.w = fmaf(a, v1.w, o1.w);
      }

      // ---- epilogue: bias + residual from global x at output flat offset ----
      const int n = n0 + lane;
      const size_t base = (size_t)b * CHW + (size_t)n * NC + c0;
      const float4* __restrict__ xr = (const float4*)(x + base);
      const float4 x0 = xr[0];
      const float4 x1 = xr[1];
      float4 r0, r1;
      r0.x = o0.x + bo0.x + x0.x; r0.y = o0.y + bo0.y + x0.y;
      r0.z = o0.z + bo0.z + x0.z; r0.w = o0.w + bo0.w + x0.w;
      r1.x = o1.x + bo1.x + x1.x; r1.y = o1.y + bo1.y + x1.y;
      r1.z = o1.z + bo1.z + x1.z; r1.w = o1.w + bo1.w + x1.w;

      float4* __restrict__ op = (float4*)(out + base);
      op[0] = r0;
      op[1] = r1;
    }
    __syncthreads();   // protect qs/aw before next rep (block-uniform path)
  }
}

extern "C" void kernel_launch(void* const* d_in, const int* in_sizes, int n_in,
                              void* d_out, int out_size, void* d_ws, size_t ws_size,
                              hipStream_t stream) {
  const float* x  = (const float*)d_in[0];
  const float* z  = (const float*)d_in[1];
  const float* Wk = (const float*)d_in[2];
  const float* bk = (const float*)d_in[3];
  const float* Wv = (const float*)d_in[4];
  const float* bv = (const float*)d_in[5];
  const float* Wo = (const float*)d_in[6];
  const float* bo = (const float*)d_in[7];
  float* out = (float*)d_out;

  float* ws = (float*)d_ws;
  float* kt = ws;                    // NB*NKV floats, [b][h][c][m]
  float* vw = ws + NB * NKV;         // NB*NKV floats, [b][g][c]

  kv_proj_kernel<<<dim3(NB, 12), 1024, 0, stream>>>(z, Wk, bk, Wv, bv, Wo,
                                                    kt, vw);
  // 5x identical attn launches (idempotent). attn_us = (dur - 120.7)/4.
  attn_kernel<<<dim3(NB, 25), 512, 0, stream>>>(x, kt, vw, bo, out);
  attn_kernel<<<dim3(NB, 25), 512, 0, stream>>>(x, kt, vw, bo, out);
  attn_kernel<<<dim3(NB, 25), 512, 0, stream>>>(x, kt, vw, bo, out);
  attn_kernel<<<dim3(NB, 25), 512, 0, stream>>>(x, kt, vw, bo, out);
  attn_kernel<<<dim3(NB, 25), 512, 0, stream>>>(x, kt, vw, bo, out);
}

// Round 11
// 164.192 us; speedup vs baseline: 1.2755x; 1.2755x over previous
//
#include <hip/hip_runtime.h>
#include <math.h>

// Problem constants
#define NB 32
#define NC 64
#define NHW 3136          // 56*56
#define NM 6
#define NDIM 192
#define NHEADS 8
#define NINNER 512        // NHEADS*NC
#define NKV 3072          // NHEADS*NM*NC per batch
#define CHW (NC * NHW)    // 200704
#define NG 48             // NHEADS*NM

// ---------------------------------------------------------------------------
// MEASUREMENT ROUND 2: kv_proj reverted to the R6 design (256-thread blocks,
// grid (32,12); the split-K 1024-thread version regressed ~16 µs). kv
// launched 5x (idempotent), attn 1x (unchanged, measured 22.2 µs).
//   kv_R6 = (dur - 82 - 22.2) / 4
// ---------------------------------------------------------------------------
__global__ __launch_bounds__(256) void kv_proj_kernel(
    const float* __restrict__ z, const float* __restrict__ Wk,
    const float* __restrict__ bk, const float* __restrict__ Wv,
    const float* __restrict__ bv, const float* __restrict__ Wo,
    float* __restrict__ kt, float* __restrict__ vw) {
  const int b = blockIdx.x;
  const int chunk = blockIdx.y;
  const int tid = threadIdx.x;
  const int idx = chunk * 256 + tid;   // raw flat 0..3071
  const int mtok = chunk >> 1;         // raw row (uniform per block)
  const int i = idx & 511;             // raw col (inner)

  __shared__ float vs[256];

  const float* __restrict__ zr = z + b * (NM * NDIM) + mtok * NDIM;  // uniform

  float ak0 = bk[i], ak1 = 0.f, av0 = bv[i], av1 = 0.f;
  #pragma unroll 8
  for (int d = 0; d < NDIM; d += 2) {
    const float z0 = zr[d], z1 = zr[d + 1];
    ak0 = fmaf(z0, Wk[d * NINNER + i], ak0);
    ak1 = fmaf(z1, Wk[(d + 1) * NINNER + i], ak1);
    av0 = fmaf(z0, Wv[d * NINNER + i], av0);
    av1 = fmaf(z1, Wv[(d + 1) * NINNER + i], av1);
  }
  // Reshape-view decomposition of the raw flat index idx -> kt[h][cc][mm]
  {
    const int h2 = idx / 384;
    const int mm2 = (idx >> 6) % 6;
    const int cc2 = idx & 63;
    kt[b * NKV + h2 * (NC * NM) + cc2 * NM + mm2] = ak0 + ak1;
  }
  vs[tid] = av0 + av1;
  __syncthreads();

  const int gl = tid >> 6;             // 0..3 (uniform per wave)
  const int c = tid & 63;
  const int g = chunk * 4 + gl;        // 0..47
  const int h = g / 6;
  float a0 = 0.f, a1 = 0.f;
  #pragma unroll 8
  for (int cc = 0; cc < NC; cc += 2) {
    a0 = fmaf(vs[gl * 64 + cc],     Wo[(h * NC + cc) * NC + c],     a0);
    a1 = fmaf(vs[gl * 64 + cc + 1], Wo[(h * NC + cc + 1) * NC + c], a1);
  }
  vw[b * NKV + g * NC + c] = a0 + a1;
}

// ---------------------------------------------------------------------------
// Kernel 2: attention — byte-identical to R9 (2 tiles per block, measured
// 22.2 µs). DO NOT TOUCH this round (it's the known in the system).
// ---------------------------------------------------------------------------
__global__ __launch_bounds__(512, 4) void attn_kernel(
    const float* __restrict__ x, const float* __restrict__ kt,
    const float* __restrict__ vw, const float* __restrict__ bo,
    float* __restrict__ out) {
  const int b = blockIdx.x;
  const int lane = threadIdx.x & 63;
  const int w = __builtin_amdgcn_readfirstlane((int)(threadIdx.x >> 6));  // 0..7
  const float* __restrict__ xb = x + (size_t)b * CHW;

  __shared__ float qs[NC][64];   // [c][n_local], 16 KB
  __shared__ float aw[NG][64];   // [g][n_local], 12 KB

  const float* __restrict__ kh = kt + b * NKV + w * (NC * NM);  // uniform
  const int c0 = w * 8;
  const float* __restrict__ vb = vw + b * NKV + c0;             // uniform
  const float4 bo0 = *(const float4*)(bo + c0);
  const float4 bo1 = *(const float4*)(bo + c0 + 4);
  const float scale = 0.125f;  // 64^-0.5

  #pragma unroll 1
  for (int rep = 0; rep < 2; ++rep) {
    const int tile = blockIdx.y * 2 + rep;   // block-uniform
    if (tile < 49) {
      const int n0 = tile * 64;

      // ---- stage q tile: 2 coalesced float4 per thread ----
      {
        const int tc = threadIdx.x >> 4;          // 0..31
        const int tn4 = (threadIdx.x & 15) * 4;   // 0..60
        #pragma unroll
        for (int r2 = 0; r2 < 2; ++r2) {
          const int c = tc + r2 * 32;
          *(float4*)(&qs[c][tn4]) =
              *(const float4*)(xb + (size_t)c * NHW + n0 + tn4);
        }
      }
      __syncthreads();

      // ---- phase 1: head w; kt head block = 384 sequential floats ----
      float d[NM];
      #pragma unroll
      for (int mm = 0; mm < NM; ++mm) d[mm] = 0.f;

      #pragma unroll 8
      for (int cc = 0; cc < NC; ++cc) {
        const float qv = qs[cc][lane];       // ds_read_b32, conflict-free
        #pragma unroll
        for (int mm = 0; mm < NM; ++mm)
          d[mm] = fmaf(qv, kh[cc * NM + mm], d[mm]);
      }

      {
        float mx = d[0];
        #pragma unroll
        for (int mm = 1; mm < NM; ++mm) mx = fmaxf(mx, d[mm]);
        float e[NM], ssum = 0.f;
        #pragma unroll
        for (int mm = 0; mm < NM; ++mm) {
          e[mm] = __expf((d[mm] - mx) * scale);
          ssum += e[mm];
        }
        const float r = 1.0f / ssum;
        #pragma unroll
        for (int mm = 0; mm < NM; ++mm) aw[w * NM + mm][lane] = e[mm] * r;
      }
      __syncthreads();

      // ---- phase 2: channels [8w, 8w+8) over all 48 (h,m) ----
      float4 o0 = {0, 0, 0, 0}, o1 = {0, 0, 0, 0};
      #pragma unroll 4
      for (int g = 0; g < NG; ++g) {
        const float a = aw[g][lane];         // ds_read_b32, conflict-free
        const float4 v0 = *(const float4*)(vb + g * NC);
        const float4 v1 = *(const float4*)(vb + g * NC + 4);
        o0.x = fmaf(a, v0.x, o0.x); o0.y = fmaf(a, v0.y, o0.y);
        o0.z = fmaf(a, v0.z, o0.z); o0.w = fmaf(a, v0.w, o0.w);
        o1.x = fmaf(a, v1.x, o1.x); o1.y = fmaf(a, v1.y, o1.y);
        o1.z = fmaf(a, v1.z, o1.z); o1.w = fmaf(a, v1.w, o1.w);
      }

      // ---- epilogue: bias + residual from global x at output flat offset ----
      const int n = n0 + lane;
      const size_t base = (size_t)b * CHW + (size_t)n * NC + c0;
      const float4* __restrict__ xr = (const float4*)(x + base);
      const float4 x0 = xr[0];
      const float4 x1 = xr[1];
      float4 r0, r1;
      r0.x = o0.x + bo0.x + x0.x; r0.y = o0.y + bo0.y + x0.y;
      r0.z = o0.z + bo0.z + x0.z; r0.w = o0.w + bo0.w + x0.w;
      r1.x = o1.x + bo1.x + x1.x; r1.y = o1.y + bo1.y + x1.y;
      r1.z = o1.z + bo1.z + x1.z; r1.w = o1.w + bo1.w + x1.w;

      float4* __restrict__ op = (float4*)(out + base);
      op[0] = r0;
      op[1] = r1;
    }
    __syncthreads();   // protect qs/aw before next rep (block-uniform path)
  }
}

extern "C" void kernel_launch(void* const* d_in, const int* in_sizes, int n_in,
                              void* d_out, int out_size, void* d_ws, size_t ws_size,
                              hipStream_t stream) {
  const float* x  = (const float*)d_in[0];
  const float* z  = (const float*)d_in[1];
  const float* Wk = (const float*)d_in[2];
  const float* bk = (const float*)d_in[3];
  const float* Wv = (const float*)d_in[4];
  const float* bv = (const float*)d_in[5];
  const float* Wo = (const float*)d_in[6];
  const float* bo = (const float*)d_in[7];
  float* out = (float*)d_out;

  float* ws = (float*)d_ws;
  float* kt = ws;                    // NB*NKV floats, [b][h][c][m]
  float* vw = ws + NB * NKV;         // NB*NKV floats, [b][g][c]

  // 5x identical kv launches (idempotent). kv_us = (dur - 82 - 22.2)/4.
  kv_proj_kernel<<<dim3(NB, 12), 256, 0, stream>>>(z, Wk, bk, Wv, bv, Wo, kt, vw);
  kv_proj_kernel<<<dim3(NB, 12), 256, 0, stream>>>(z, Wk, bk, Wv, bv, Wo, kt, vw);
  kv_proj_kernel<<<dim3(NB, 12), 256, 0, stream>>>(z, Wk, bk, Wv, bv, Wo, kt, vw);
  kv_proj_kernel<<<dim3(NB, 12), 256, 0, stream>>>(z, Wk, bk, Wv, bv, Wo, kt, vw);
  kv_proj_kernel<<<dim3(NB, 12), 256, 0, stream>>>(z, Wk, bk, Wv, bv, Wo, kt, vw);
  attn_kernel<<<dim3(NB, 25), 512, 0, stream>>>(x, kt, vw, bo, out);
}

// Round 12
// 119.659 us; speedup vs baseline: 1.7502x; 1.3722x over previous
//
#include <hip/hip_runtime.h>
#include <math.h>

// Problem constants
#define NB 32
#define NC 64
#define NHW 3136          // 56*56
#define NM 6
#define NDIM 192
#define NHEADS 8
#define NINNER 512        // NHEADS*NC
#define NKV 3072          // NHEADS*NM*NC per batch
#define CHW (NC * NHW)    // 200704
#define NG 48             // NHEADS*NM

// ---------------------------------------------------------------------------
// Kernel 1: kt + VW, 2-way split-K over d, 512-thread blocks, grid (32,12).
//   Thread groups s = tid>>8 (0/1) accumulate d in [96s, 96s+96) for the
//   256 raw idx of this chunk. 4 KB LDS partials, one reduce barrier,
//   then threads 0..255 add bias, store kt (reshape-transposed) + compute VW.
//   (R7's 1024-thr/4-way version regressed: too much idle + barrier weight.
//    This one: 2x TLP vs R6 [3 waves/SIMD], half the chain depth.)
//   kt[h][cc][mm] = raw[h*384 + mm*64 + cc]  (stored at h*384 + cc*6 + mm)
//   VW[g][c] = sum_cc v_raw[g*64+cc] * Wo[(h*64+cc)*64+c], g = h*6+m.
// ---------------------------------------------------------------------------
__global__ __launch_bounds__(512) void kv_proj_kernel(
    const float* __restrict__ z, const float* __restrict__ Wk,
    const float* __restrict__ bk, const float* __restrict__ Wv,
    const float* __restrict__ bv, const float* __restrict__ Wo,
    float* __restrict__ kt, float* __restrict__ vw) {
  const int b = blockIdx.x;
  const int chunk = blockIdx.y;
  const int tid = threadIdx.x;
  const int u = tid & 255;
  const int s = __builtin_amdgcn_readfirstlane(tid >> 8);  // 0/1, SGPR
  const int idx = chunk * 256 + u;     // raw flat 0..3071
  const int mtok = chunk >> 1;         // raw row (uniform per block)
  const int i = idx & 511;             // raw col (inner)

  __shared__ float kp[512];
  __shared__ float vp[512];
  __shared__ float vs[256];

  const float* __restrict__ zr = z + b * (NM * NDIM) + mtok * NDIM;  // uniform

  float ak0 = 0.f, ak1 = 0.f, av0 = 0.f, av1 = 0.f;
  const int dlo = s * 96;
  #pragma unroll 8
  for (int d = dlo; d < dlo + 96; d += 2) {
    const float z0 = zr[d], z1 = zr[d + 1];
    ak0 = fmaf(z0, Wk[d * NINNER + i], ak0);
    ak1 = fmaf(z1, Wk[(d + 1) * NINNER + i], ak1);
    av0 = fmaf(z0, Wv[d * NINNER + i], av0);
    av1 = fmaf(z1, Wv[(d + 1) * NINNER + i], av1);
  }
  kp[tid] = ak0 + ak1;
  vp[tid] = av0 + av1;
  __syncthreads();

  if (tid < 256) {
    const float kf = bk[i] + (kp[u] + kp[256 + u]);
    const float vf = bv[i] + (vp[u] + vp[256 + u]);
    // Reshape-view decomposition of raw flat idx -> kt[h][cc][mm]
    const int h2 = idx / 384;
    const int mm2 = (idx >> 6) % 6;
    const int cc2 = idx & 63;
    kt[b * NKV + h2 * (NC * NM) + cc2 * NM + mm2] = kf;
    vs[u] = vf;
  }
  __syncthreads();

  if (tid < 256) {
    const int gl = u >> 6;             // 0..3 (uniform per wave)
    const int c = u & 63;
    const int g = chunk * 4 + gl;      // 0..47
    const int h = g / 6;
    float a0 = 0.f, a1 = 0.f;
    #pragma unroll 8
    for (int cc = 0; cc < NC; cc += 2) {
      a0 = fmaf(vs[gl * 64 + cc],     Wo[(h * NC + cc) * NC + c],     a0);
      a1 = fmaf(vs[gl * 64 + cc + 1], Wo[(h * NC + cc + 1) * NC + c], a1);
    }
    vw[b * NKV + g * NC + c] = a0 + a1;
  }
}

// ---------------------------------------------------------------------------
// Kernel 2: attention — byte-identical to R9/R10 (2 tiles per block,
// measured 22.2 µs). Frozen this round.
// ---------------------------------------------------------------------------
__global__ __launch_bounds__(512, 4) void attn_kernel(
    const float* __restrict__ x, const float* __restrict__ kt,
    const float* __restrict__ vw, const float* __restrict__ bo,
    float* __restrict__ out) {
  const int b = blockIdx.x;
  const int lane = threadIdx.x & 63;
  const int w = __builtin_amdgcn_readfirstlane((int)(threadIdx.x >> 6));  // 0..7
  const float* __restrict__ xb = x + (size_t)b * CHW;

  __shared__ float qs[NC][64];   // [c][n_local], 16 KB
  __shared__ float aw[NG][64];   // [g][n_local], 12 KB

  const float* __restrict__ kh = kt + b * NKV + w * (NC * NM);  // uniform
  const int c0 = w * 8;
  const float* __restrict__ vb = vw + b * NKV + c0;             // uniform
  const float4 bo0 = *(const float4*)(bo + c0);
  const float4 bo1 = *(const float4*)(bo + c0 + 4);
  const float scale = 0.125f;  // 64^-0.5

  #pragma unroll 1
  for (int rep = 0; rep < 2; ++rep) {
    const int tile = blockIdx.y * 2 + rep;   // block-uniform
    if (tile < 49) {
      const int n0 = tile * 64;

      // ---- stage q tile: 2 coalesced float4 per thread ----
      {
        const int tc = threadIdx.x >> 4;          // 0..31
        const int tn4 = (threadIdx.x & 15) * 4;   // 0..60
        #pragma unroll
        for (int r2 = 0; r2 < 2; ++r2) {
          const int c = tc + r2 * 32;
          *(float4*)(&qs[c][tn4]) =
              *(const float4*)(xb + (size_t)c * NHW + n0 + tn4);
        }
      }
      __syncthreads();

      // ---- phase 1: head w; kt head block = 384 sequential floats ----
      float d[NM];
      #pragma unroll
      for (int mm = 0; mm < NM; ++mm) d[mm] = 0.f;

      #pragma unroll 8
      for (int cc = 0; cc < NC; ++cc) {
        const float qv = qs[cc][lane];       // ds_read_b32, conflict-free
        #pragma unroll
        for (int mm = 0; mm < NM; ++mm)
          d[mm] = fmaf(qv, kh[cc * NM + mm], d[mm]);
      }

      {
        float mx = d[0];
        #pragma unroll
        for (int mm = 1; mm < NM; ++mm) mx = fmaxf(mx, d[mm]);
        float e[NM], ssum = 0.f;
        #pragma unroll
        for (int mm = 0; mm < NM; ++mm) {
          e[mm] = __expf((d[mm] - mx) * scale);
          ssum += e[mm];
        }
        const float r = 1.0f / ssum;
        #pragma unroll
        for (int mm = 0; mm < NM; ++mm) aw[w * NM + mm][lane] = e[mm] * r;
      }
      __syncthreads();

      // ---- phase 2: channels [8w, 8w+8) over all 48 (h,m) ----
      float4 o0 = {0, 0, 0, 0}, o1 = {0, 0, 0, 0};
      #pragma unroll 4
      for (int g = 0; g < NG; ++g) {
        const float a = aw[g][lane];         // ds_read_b32, conflict-free
        const float4 v0 = *(const float4*)(vb + g * NC);
        const float4 v1 = *(const float4*)(vb + g * NC + 4);
        o0.x = fmaf(a, v0.x, o0.x); o0.y = fmaf(a, v0.y, o0.y);
        o0.z = fmaf(a, v0.z, o0.z); o0.w = fmaf(a, v0.w, o0.w);
        o1.x = fmaf(a, v1.x, o1.x); o1.y = fmaf(a, v1.y, o1.y);
        o1.z = fmaf(a, v1.z, o1.z); o1.w = fmaf(a, v1.w, o1.w);
      }

      // ---- epilogue: bias + residual from global x at output flat offset ----
      const int n = n0 + lane;
      const size_t base = (size_t)b * CHW + (size_t)n * NC + c0;
      const float4* __restrict__ xr = (const float4*)(x + base);
      const float4 x0 = xr[0];
      const float4 x1 = xr[1];
      float4 r0, r1;
      r0.x = o0.x + bo0.x + x0.x; r0.y = o0.y + bo0.y + x0.y;
      r0.z = o0.z + bo0.z + x0.z; r0.w = o0.w + bo0.w + x0.w;
      r1.x = o1.x + bo1.x + x1.x; r1.y = o1.y + bo1.y + x1.y;
      r1.z = o1.z + bo1.z + x1.z; r1.w = o1.w + bo1.w + x1.w;

      float4* __restrict__ op = (float4*)(out + base);
      op[0] = r0;
      op[1] = r1;
    }
    __syncthreads();   // protect qs/aw before next rep (block-uniform path)
  }
}

extern "C" void kernel_launch(void* const* d_in, const int* in_sizes, int n_in,
                              void* d_out, int out_size, void* d_ws, size_t ws_size,
                              hipStream_t stream) {
  const float* x  = (const float*)d_in[0];
  const float* z  = (const float*)d_in[1];
  const float* Wk = (const float*)d_in[2];
  const float* bk = (const float*)d_in[3];
  const float* Wv = (const float*)d_in[4];
  const float* bv = (const float*)d_in[5];
  const float* Wo = (const float*)d_in[6];
  const float* bo = (const float*)d_in[7];
  float* out = (float*)d_out;

  float* ws = (float*)d_ws;
  float* kt = ws;                    // NB*NKV floats, [b][h][c][m]
  float* vw = ws + NB * NKV;         // NB*NKV floats, [b][g][c]

  kv_proj_kernel<<<dim3(NB, 12), 512, 0, stream>>>(z, Wk, bk, Wv, bv, Wo,
                                                   kt, vw);
  attn_kernel<<<dim3(NB, 25), 512, 0, stream>>>(x, kt, vw, bo, out);
}

// Round 13
// 119.410 us; speedup vs baseline: 1.7538x; 1.0021x over previous
//
#include <hip/hip_runtime.h>
#include <math.h>

// Problem constants
#define NB 32
#define NC 64
#define NHW 3136          // 56*56
#define NM 6
#define NDIM 192
#define NHEADS 8
#define NINNER 512        // NHEADS*NC
#define NKV 3072          // NHEADS*NM*NC per batch
#define CHW (NC * NHW)    // 200704
#define NG 48             // NHEADS*NM

// ---------------------------------------------------------------------------
// Kernel 1: kv6 design (VERBATIM from R10/R11 — measured ~12.3 µs; both
// split-K variants measured SLOWER, 17-18 µs: kv is not chain-latency-bound).
// kt[h][cc][mm] = raw[h*384+mm*64+cc] stored at h*384+cc*6+mm;
// VW[g][c] = sum_cc v_raw[g*64+cc]*Wo[(h*64+cc)*64+c], g=h*6+m.
// grid (32,12) x 256.
// ---------------------------------------------------------------------------
__global__ __launch_bounds__(256) void kv_proj_kernel(
    const float* __restrict__ z, const float* __restrict__ Wk,
    const float* __restrict__ bk, const float* __restrict__ Wv,
    const float* __restrict__ bv, const float* __restrict__ Wo,
    float* __restrict__ kt, float* __restrict__ vw) {
  const int b = blockIdx.x;
  const int chunk = blockIdx.y;
  const int tid = threadIdx.x;
  const int idx = chunk * 256 + tid;   // raw flat 0..3071
  const int mtok = chunk >> 1;         // raw row (uniform per block)
  const int i = idx & 511;             // raw col (inner)

  __shared__ float vs[256];

  const float* __restrict__ zr = z + b * (NM * NDIM) + mtok * NDIM;  // uniform

  float ak0 = bk[i], ak1 = 0.f, av0 = bv[i], av1 = 0.f;
  #pragma unroll 8
  for (int d = 0; d < NDIM; d += 2) {
    const float z0 = zr[d], z1 = zr[d + 1];
    ak0 = fmaf(z0, Wk[d * NINNER + i], ak0);
    ak1 = fmaf(z1, Wk[(d + 1) * NINNER + i], ak1);
    av0 = fmaf(z0, Wv[d * NINNER + i], av0);
    av1 = fmaf(z1, Wv[(d + 1) * NINNER + i], av1);
  }
  {
    const int h2 = idx / 384;
    const int mm2 = (idx >> 6) % 6;
    const int cc2 = idx & 63;
    kt[b * NKV + h2 * (NC * NM) + cc2 * NM + mm2] = ak0 + ak1;
  }
  vs[tid] = av0 + av1;
  __syncthreads();

  const int gl = tid >> 6;             // 0..3 (uniform per wave)
  const int c = tid & 63;
  const int g = chunk * 4 + gl;        // 0..47
  const int h = g / 6;
  float a0 = 0.f, a1 = 0.f;
  #pragma unroll 8
  for (int cc = 0; cc < NC; cc += 2) {
    a0 = fmaf(vs[gl * 64 + cc],     Wo[(h * NC + cc) * NC + c],     a0);
    a1 = fmaf(vs[gl * 64 + cc + 1], Wo[(h * NC + cc + 1) * NC + c], a1);
  }
  vw[b * NKV + g * NC + c] = a0 + a1;
}

// ---------------------------------------------------------------------------
// Kernel 2: attention, 2 tiles/block (measured 22.2 µs) + q-prefetch
// pipelining: tile t+1's q global loads are issued right after tile t's
// qs-write, so their latency hides under tile t's phase1+phase2. Registers
// -> LDS after the loop-end barrier. All other structure identical to R9.
// ---------------------------------------------------------------------------
__global__ __launch_bounds__(512, 4) void attn_kernel(
    const float* __restrict__ x, const float* __restrict__ kt,
    const float* __restrict__ vw, const float* __restrict__ bo,
    float* __restrict__ out) {
  const int b = blockIdx.x;
  const int lane = threadIdx.x & 63;
  const int w = __builtin_amdgcn_readfirstlane((int)(threadIdx.x >> 6));  // 0..7
  const float* __restrict__ xb = x + (size_t)b * CHW;

  __shared__ float qs[NC][64];   // [c][n_local], 16 KB
  __shared__ float aw[NG][64];   // [g][n_local], 12 KB

  const float* __restrict__ kh = kt + b * NKV + w * (NC * NM);  // uniform
  const int c0 = w * 8;
  const float* __restrict__ vb = vw + b * NKV + c0;             // uniform
  const float4 bo0 = *(const float4*)(bo + c0);
  const float4 bo1 = *(const float4*)(bo + c0 + 4);
  const float scale = 0.125f;  // 64^-0.5

  // q-stage decomposition (per thread: channels tc and tc+32, 4 n's)
  const int tc = threadIdx.x >> 4;          // 0..31
  const int tn4 = (threadIdx.x & 15) * 4;   // 0..60

  // ---- prefetch tile 0's q into registers ----
  float4 pf0, pf1;
  {
    const int n0 = blockIdx.y * 128;
    pf0 = *(const float4*)(xb + (size_t)tc * NHW + n0 + tn4);
    pf1 = *(const float4*)(xb + (size_t)(tc + 32) * NHW + n0 + tn4);
  }

  #pragma unroll 1
  for (int rep = 0; rep < 2; ++rep) {
    const int tile = blockIdx.y * 2 + rep;   // block-uniform
    if (tile < 49) {
      const int n0 = tile * 64;

      // ---- write staged q regs -> LDS; issue next tile's prefetch ----
      *(float4*)(&qs[tc][tn4]) = pf0;
      *(float4*)(&qs[tc + 32][tn4]) = pf1;
      if (rep == 0 && tile + 1 < 49) {       // block-uniform guard
        const int n1 = n0 + 64;
        pf0 = *(const float4*)(xb + (size_t)tc * NHW + n1 + tn4);
        pf1 = *(const float4*)(xb + (size_t)(tc + 32) * NHW + n1 + tn4);
      }
      __syncthreads();

      // ---- phase 1: head w; kt head block = 384 sequential floats ----
      float d[NM];
      #pragma unroll
      for (int mm = 0; mm < NM; ++mm) d[mm] = 0.f;

      #pragma unroll 8
      for (int cc = 0; cc < NC; ++cc) {
        const float qv = qs[cc][lane];       // ds_read_b32, conflict-free
        #pragma unroll
        for (int mm = 0; mm < NM; ++mm)
          d[mm] = fmaf(qv, kh[cc * NM + mm], d[mm]);
      }

      {
        float mx = d[0];
        #pragma unroll
        for (int mm = 1; mm < NM; ++mm) mx = fmaxf(mx, d[mm]);
        float e[NM], ssum = 0.f;
        #pragma unroll
        for (int mm = 0; mm < NM; ++mm) {
          e[mm] = __expf((d[mm] - mx) * scale);
          ssum += e[mm];
        }
        const float r = 1.0f / ssum;
        #pragma unroll
        for (int mm = 0; mm < NM; ++mm) aw[w * NM + mm][lane] = e[mm] * r;
      }
      __syncthreads();

      // ---- phase 2: channels [8w, 8w+8) over all 48 (h,m) ----
      float4 o0 = {0, 0, 0, 0}, o1 = {0, 0, 0, 0};
      #pragma unroll 4
      for (int g = 0; g < NG; ++g) {
        const float a = aw[g][lane];         // ds_read_b32, conflict-free
        const float4 v0 = *(const float4*)(vb + g * NC);
        const float4 v1 = *(const float4*)(vb + g * NC + 4);
        o0.x = fmaf(a, v0.x, o0.x); o0.y = fmaf(a, v0.y, o0.y);
        o0.z = fmaf(a, v0.z, o0.z); o0.w = fmaf(a, v0.w, o0.w);
        o1.x = fmaf(a, v1.x, o1.x); o1.y = fmaf(a, v1.y, o1.y);
        o1.z = fmaf(a, v1.z, o1.z); o1.w = fmaf(a, v1.w, o1.w);
      }

      // ---- epilogue: bias + residual from global x at output flat offset ----
      const int n = n0 + lane;
      const size_t base = (size_t)b * CHW + (size_t)n * NC + c0;
      const float4* __restrict__ xr = (const float4*)(x + base);
      const float4 x0 = xr[0];
      const float4 x1 = xr[1];
      float4 r0, r1;
      r0.x = o0.x + bo0.x + x0.x; r0.y = o0.y + bo0.y + x0.y;
      r0.z = o0.z + bo0.z + x0.z; r0.w = o0.w + bo0.w + x0.w;
      r1.x = o1.x + bo1.x + x1.x; r1.y = o1.y + bo1.y + x1.y;
      r1.z = o1.z + bo1.z + x1.z; r1.w = o1.w + bo1.w + x1.w;

      float4* __restrict__ op = (float4*)(out + base);
      op[0] = r0;
      op[1] = r1;
    }
    __syncthreads();   // qs free for next rep's staged write
  }
}

extern "C" void kernel_launch(void* const* d_in, const int* in_sizes, int n_in,
                              void* d_out, int out_size, void* d_ws, size_t ws_size,
                              hipStream_t stream) {
  const float* x  = (const float*)d_in[0];
  const float* z  = (const float*)d_in[1];
  const float* Wk = (const float*)d_in[2];
  const float* bk = (const float*)d_in[3];
  const float* Wv = (const float*)d_in[4];
  const float* bv = (const float*)d_in[5];
  const float* Wo = (const float*)d_in[6];
  const float* bo = (const float*)d_in[7];
  float* out = (float*)d_out;

  float* ws = (float*)d_ws;
  float* kt = ws;                    // NB*NKV floats, [b][h][c][m]
  float* vw = ws + NB * NKV;         // NB*NKV floats, [b][g][c]

  kv_proj_kernel<<<dim3(NB, 12), 256, 0, stream>>>(z, Wk, bk, Wv, bv, Wo,
                                                   kt, vw);
  attn_kernel<<<dim3(NB, 25), 512, 0, stream>>>(x, kt, vw, bo, out);
}